// Round 23
// baseline (56.006 us; speedup 1.0000x reference)
//
#include <hip/hip_runtime.h>
#include <hip/hip_bf16.h>

typedef __attribute__((ext_vector_type(8))) short short8;
typedef __attribute__((ext_vector_type(4))) float f32x4;
typedef __attribute__((ext_vector_type(2))) unsigned uint2v;

#define MFMA16(a, b, c) __builtin_amdgcn_mfma_f32_16x16x32_bf16((a), (b), (c), 0, 0, 0)

constexpr int Bc = 2, Lc = 2048, Hc = 16, Ec = 64;
constexpr float LOG2E = 1.4426950408889634f;
constexpr float SCALE2 = 0.125f * LOG2E;   // fold log2(e): scores in log2 units
constexpr float NEGBIG = -3.0e38f;

union SW { short8 s8; unsigned u[4]; float4 f4; };

__device__ __forceinline__ unsigned cvtpk(float lo, float hi) {
  unsigned r;
  asm("v_cvt_pk_bf16_f32 %0, %1, %2" : "=v"(r) : "v"(lo), "v"(hi));
  return r;
}
__device__ __forceinline__ float exp2v(float x) {
  float r;
  asm("v_exp_f32 %0, %1" : "=v"(r) : "v"(x));
  return r;
}
__device__ __forceinline__ void plswap32(unsigned& a, unsigned& b) {
  uint2v r = __builtin_amdgcn_permlane32_swap(a, b, false, false);
  a = r[0]; b = r[1];
}
__device__ __forceinline__ void plswap16(unsigned& a, unsigned& b) {
  uint2v r = __builtin_amdgcn_permlane16_swap(a, b, false, false);
  a = r[0]; b = r[1];
}
__device__ __forceinline__ float bflymax(float x) {
  unsigned a = __builtin_bit_cast(unsigned, x), b = a;
  plswap16(a, b);
  float y = fmaxf(__builtin_bit_cast(float, a), __builtin_bit_cast(float, b));
  a = __builtin_bit_cast(unsigned, y); b = a;
  plswap32(a, b);
  return fmaxf(__builtin_bit_cast(float, a), __builtin_bit_cast(float, b));
}

// Prepass:
//  blocks [0,1024): K -> chunk-major Kc[bh][c]: chunk = 128 slots of 16B;
//    slot (j,nn), j in [0,8): K row c*16+pi(nn), elements j*8..j*8+7 (pi =
//    swap bits 2,3). Lane l (=j0*16+nn, j0 in [0,4)) writes slots l (els
//    j0*8..+7) and l+64 (els 32+j0*8..+7).
//  blocks [1024,2048): V -> chunk-major Vt[bh][s/16][e][16] bf16.
__global__ __launch_bounds__(256)
void prep(const float* __restrict__ K, const float* __restrict__ V,
          uint4* __restrict__ Kc, unsigned short* __restrict__ Vt) {
  const int bid = blockIdx.x;
  const int t = threadIdx.x;
  const int l = t & 63;
  if (bid < 1024) {
    const int vw = bid * 4 + (t >> 6);   // 0..4095 = bh*128 + c
    const int bh = vw >> 7;
    const int c = vw & 127;
    const int j = l >> 4, nn = l & 15;
    const int pnn = (nn & 3) | ((nn & 4) << 1) | ((nn & 8) >> 1);  // pi(nn)
    const float* kp = K + ((size_t)((bh >> 4) * Lc + c * 16 + pnn) * Hc +
                           (bh & 15)) * Ec + j * 8;
    float4 x0 = reinterpret_cast<const float4*>(kp)[0];
    float4 x1 = reinterpret_cast<const float4*>(kp)[1];
    float4 y0 = reinterpret_cast<const float4*>(kp + 32)[0];
    float4 y1 = reinterpret_cast<const float4*>(kp + 32)[1];
    uint4 ox, oy;
    ox.x = cvtpk(x0.x, x0.y); ox.y = cvtpk(x0.z, x0.w);
    ox.z = cvtpk(x1.x, x1.y); ox.w = cvtpk(x1.z, x1.w);
    oy.x = cvtpk(y0.x, y0.y); oy.y = cvtpk(y0.z, y0.w);
    oy.z = cvtpk(y1.x, y1.y); oy.w = cvtpk(y1.z, y1.w);
    Kc[(size_t)vw * 128 + l] = ox;
    Kc[(size_t)vw * 128 + l + 64] = oy;
  } else {
    const int vw = (bid - 1024) * 4 + (t >> 6);   // bh*128 + chunk
    const int bh = vw >> 7;
    const int s0 = (vw & 127) * 16;
    const float* vp = V + ((size_t)(bh >> 4) * Lc + s0) * (Hc * Ec) +
                      (bh & 15) * Ec + l;
    float va[16];
    #pragma unroll
    for (int j = 0; j < 16; ++j) va[j] = vp[j * (Hc * Ec)];
    uint4 o0, o1;
    o0.x = cvtpk(va[0], va[1]);   o0.y = cvtpk(va[2], va[3]);
    o0.z = cvtpk(va[4], va[5]);   o0.w = cvtpk(va[6], va[7]);
    o1.x = cvtpk(va[8], va[9]);   o1.y = cvtpk(va[10], va[11]);
    o1.z = cvtpk(va[12], va[13]); o1.w = cvtpk(va[14], va[15]);
    uint4* dst = reinterpret_cast<uint4*>(Vt + ((size_t)vw * 64 + l) * 16);
    dst[0] = o0;
    dst[1] = o1;
  }
}

__global__ __launch_bounds__(512, 2)
void attn_fwd(const float* __restrict__ Qg, const unsigned short* __restrict__ Kc,
              const unsigned short* __restrict__ Vt, float* __restrict__ Og) {
  // NO LDS in the main loop — K and V fragments stream from L2/L1 into regs.
  __shared__ __align__(16) float mscr[64 * 68 + 128];   // merge scratch only

  // XCD-locality decode (r19): all 16 pair-blocks of a bh on one XCD.
  const int bid = blockIdx.x;
  const int pair = bid >> 5;
  const int bh = bid & 31;
  const int h = bh & (Hc - 1);
  const int b = bh >> 4;
  const int iLo = pair;
  const int QbL = iLo * 64;
  const int QbH = (31 - pair) * 64;
  const int RL = (iLo + 2) >> 1;              // lo-tile rounds; RL + RH = 17

  const int t = threadIdx.x;
  const int w = t >> 6;        // 0..7
  const int qsub = w & 3;      // q sub-block (16 rows)
  const int par = w >> 2;      // 64-s half of the 128-row tile
  const int l = t & 63;
  const int n = l & 15;
  const int g = l >> 4;
  const int sp4 = ((g & 1) << 3) | ((g >> 1) << 2);  // pi(g)*4

  const f32x4 zero4 = {0.f, 0.f, 0.f, 0.f};
  short8 onesv;
  #pragma unroll
  for (int j = 0; j < 8; ++j) onesv[j] = (short)0x3F80;  // bf16 1.0

  // Q fragments (B-operand: col=q=lane&15, k=e=(lane>>4)*8+j)
  short8 qf[2];
  auto loadq = [&](int Qb) {
    const int q = Qb + qsub * 16 + n;
    const float* qp = Qg + ((size_t)(b * Lc + q) * Hc + h) * Ec + g * 8;
    SW a0, a1, b0, b1, r0, r1;
    a0.f4 = reinterpret_cast<const float4*>(qp)[0];
    a1.f4 = reinterpret_cast<const float4*>(qp)[1];
    b0.f4 = reinterpret_cast<const float4*>(qp + 32)[0];
    b1.f4 = reinterpret_cast<const float4*>(qp + 32)[1];
    r0.u[0] = cvtpk(a0.f4.x * SCALE2, a0.f4.y * SCALE2);
    r0.u[1] = cvtpk(a0.f4.z * SCALE2, a0.f4.w * SCALE2);
    r0.u[2] = cvtpk(a1.f4.x * SCALE2, a1.f4.y * SCALE2);
    r0.u[3] = cvtpk(a1.f4.z * SCALE2, a1.f4.w * SCALE2);
    r1.u[0] = cvtpk(b0.f4.x * SCALE2, b0.f4.y * SCALE2);
    r1.u[1] = cvtpk(b0.f4.z * SCALE2, b0.f4.w * SCALE2);
    r1.u[2] = cvtpk(b1.f4.x * SCALE2, b1.f4.y * SCALE2);
    r1.u[3] = cvtpk(b1.f4.z * SCALE2, b1.f4.w * SCALE2);
    qf[0] = r0.s8;
    qf[1] = r1.s8;
  };

  // acc[e4][r] = O^T[e = e4*16 + g*4 + r][q = n]; per-lane scalar m,l
  f32x4 acc[4] = {zero4, zero4, zero4, zero4};
  float mrun = NEGBIG, lrun = 0.f;

  // K fragments kr[cb][kc]; V fragments vr0/vr1[e4]
  SW kr[4][2];
  SW vr0[4], vr1[4];

  auto issueK = [&](int str) {
    unsigned a0 = (unsigned)((((bh * 128 + str * 8 + par * 4) * 128) + (g * 16 + n)) * 16);
    unsigned a1 = a0 + 4096;
    asm volatile(
      "global_load_dwordx4 %[r0], %[a0], %[kb]\n\t"
      "global_load_dwordx4 %[r1], %[a0], %[kb] offset:1024\n\t"
      "global_load_dwordx4 %[r2], %[a0], %[kb] offset:2048\n\t"
      "global_load_dwordx4 %[r3], %[a0], %[kb] offset:3072\n\t"
      "global_load_dwordx4 %[r4], %[a1], %[kb]\n\t"
      "global_load_dwordx4 %[r5], %[a1], %[kb] offset:1024\n\t"
      "global_load_dwordx4 %[r6], %[a1], %[kb] offset:2048\n\t"
      "global_load_dwordx4 %[r7], %[a1], %[kb] offset:3072"
      : [r0]"=&v"(kr[0][0].f4), [r1]"=&v"(kr[0][1].f4),
        [r2]"=&v"(kr[1][0].f4), [r3]"=&v"(kr[1][1].f4),
        [r4]"=&v"(kr[2][0].f4), [r5]"=&v"(kr[2][1].f4),
        [r6]"=&v"(kr[3][0].f4), [r7]"=&v"(kr[3][1].f4)
      : [a0]"v"(a0), [a1]"v"(a1), [kb]"s"(Kc)
      : "memory");
  };
  auto issueV = [&](int str) {
    unsigned a0 = (unsigned)((((bh * 128 + str * 8 + par * 4 + (g >> 1)) * 64 + n) * 32)
                             + ((g & 1) * 16));
    unsigned a1 = a0 + 4096;
    asm volatile(
      "global_load_dwordx4 %[f0], %[a0], %[vb]\n\t"
      "global_load_dwordx4 %[f1], %[a0], %[vb] offset:512\n\t"
      "global_load_dwordx4 %[f2], %[a0], %[vb] offset:1024\n\t"
      "global_load_dwordx4 %[f3], %[a0], %[vb] offset:1536\n\t"
      "global_load_dwordx4 %[f4], %[a1], %[vb]\n\t"
      "global_load_dwordx4 %[f5], %[a1], %[vb] offset:512\n\t"
      "global_load_dwordx4 %[f6], %[a1], %[vb] offset:1024\n\t"
      "global_load_dwordx4 %[f7], %[a1], %[vb] offset:1536"
      : [f0]"=&v"(vr0[0].f4), [f1]"=&v"(vr0[1].f4),
        [f2]"=&v"(vr0[2].f4), [f3]"=&v"(vr0[3].f4),
        [f4]"=&v"(vr1[0].f4), [f5]"=&v"(vr1[1].f4),
        [f6]"=&v"(vr1[2].f4), [f7]"=&v"(vr1[3].f4)
      : [a0]"v"(a0), [a1]"v"(a1), [vb]"s"(Vt)
      : "memory");
  };

  // one 64q x 128s round (wave: 16 q x 64 s half); barrier-free, pure regs.
  // Invariant at entry: K(str) 8 loads (older) + V(str) 8 loads in flight.
  auto round = [&](int Qb, int str, bool pre, int nstrN) {
    const int sb = str * 128 + par * 64;
    const int qtop = Qb + qsub * 16;
    const bool active = (sb <= qtop + 15);

    asm volatile("s_waitcnt vmcnt(8)" ::: "memory");   // K(str) complete
    __builtin_amdgcn_sched_barrier(0);

    f32x4 sc[4] = {zero4, zero4, zero4, zero4};
    if (active) {
      __builtin_amdgcn_s_setprio(1);
      #pragma unroll
      for (int kc = 0; kc < 2; ++kc)
        #pragma unroll
        for (int cb = 0; cb < 4; ++cb)
          sc[cb] = MFMA16(kr[cb][kc].s8, qf[kc], sc[cb]);
      __builtin_amdgcn_s_setprio(0);
    }
    if (pre) issueK(nstrN);   // outstanding: V(str) 8 older + K(next) 8

    SW pw0, pw1;
    pw0.f4 = float4{0, 0, 0, 0};
    pw1.f4 = float4{0, 0, 0, 0};
    if (active) {
      const int qg = qtop + n;
      if (sb + 63 > qtop) {
        #pragma unroll
        for (int cb = 0; cb < 4; ++cb)
          #pragma unroll
          for (int r = 0; r < 4; ++r)
            if (sb + cb * 16 + sp4 + r > qg) sc[cb][r] = NEGBIG;
      }
      float m8 = fmaxf(fmaxf(fmaxf(sc[0][0], sc[0][1]), fmaxf(sc[0][2], sc[0][3])),
                       fmaxf(fmaxf(sc[1][0], sc[1][1]), fmaxf(sc[1][2], sc[1][3])));
      m8 = fmaxf(m8, fmaxf(fmaxf(fmaxf(sc[2][0], sc[2][1]), fmaxf(sc[2][2], sc[2][3])),
                           fmaxf(fmaxf(sc[3][0], sc[3][1]), fmaxf(sc[3][2], sc[3][3]))));
      m8 = bflymax(m8);

      const bool resc = !__all(m8 <= mrun);
      if (resc) {
        const float mn = fmaxf(mrun, m8);
        const float afac = exp2v(mrun - mn);
        mrun = mn;
        lrun *= afac;
        #pragma unroll
        for (int e4 = 0; e4 < 4; ++e4)
          #pragma unroll
          for (int r = 0; r < 4; ++r) acc[e4][r] *= afac;
      }

      unsigned ua[4], ub[4];
      #pragma unroll
      for (int cb = 0; cb < 4; ++cb) {
        ua[cb] = cvtpk(exp2v(sc[cb][0] - mrun), exp2v(sc[cb][1] - mrun));
        ub[cb] = cvtpk(exp2v(sc[cb][2] - mrun), exp2v(sc[cb][3] - mrun));
      }
      plswap32(ua[0], ua[1]);
      plswap32(ub[0], ub[1]);
      plswap32(ua[2], ua[3]);
      plswap32(ub[2], ub[3]);
      pw0.u[0] = ua[0]; pw0.u[1] = ub[0]; pw0.u[2] = ua[1]; pw0.u[3] = ub[1];
      pw1.u[0] = ua[2]; pw1.u[1] = ub[2]; pw1.u[2] = ua[3]; pw1.u[3] = ub[3];
    }

    if (pre) { asm volatile("s_waitcnt vmcnt(8)" ::: "memory"); }  // V(str) done
    else     { asm volatile("s_waitcnt vmcnt(0)" ::: "memory"); }
    __builtin_amdgcn_sched_barrier(0);

    if (active) {
      __builtin_amdgcn_s_setprio(1);
      #pragma unroll
      for (int e4 = 0; e4 < 4; ++e4) {
        acc[e4] = MFMA16(vr0[e4].s8, pw0.s8, acc[e4]);
        acc[e4] = MFMA16(vr1[e4].s8, pw1.s8, acc[e4]);
      }
      f32x4 rs = MFMA16(onesv, pw0.s8, zero4);
      rs = MFMA16(onesv, pw1.s8, rs);
      __builtin_amdgcn_s_setprio(0);
      lrun += rs[0];
    }
    if (pre) issueV(nstrN);   // restore invariant for next round
  };

  // merge parities via dedicated scratch
  auto merge_store = [&](int Qb) {
    __syncthreads();
    const int row = qsub * 16 + n;
    if (par == 1) {
      float* base = mscr + row * 68;
      #pragma unroll
      for (int e4 = 0; e4 < 4; ++e4)
        #pragma unroll
        for (int r = 0; r < 4; ++r) base[e4 * 16 + g * 4 + r] = acc[e4][r];
      if (g == 0) {
        mscr[64 * 68 + row] = mrun;
        mscr[64 * 68 + 64 + row] = lrun;
      }
    }
    __syncthreads();
    if (par == 0) {
      const float* base = mscr + row * 68;
      const float m1 = mscr[64 * 68 + row];
      const float l1 = mscr[64 * 68 + 64 + row];
      const float mm = fmaxf(mrun, m1);
      const float a0 = exp2v(mrun - mm);
      const float a1 = exp2v(m1 - mm);
      const float inv = 1.0f / (lrun * a0 + l1 * a1);
      const int q = Qb + row;
      float* op = Og + ((size_t)(b * Lc + q) * Hc + h) * Ec;
      #pragma unroll
      for (int e4 = 0; e4 < 4; ++e4) {
        float4 v;
        v.x = (acc[e4][0] * a0 + base[e4 * 16 + g * 4 + 0] * a1) * inv;
        v.y = (acc[e4][1] * a0 + base[e4 * 16 + g * 4 + 1] * a1) * inv;
        v.z = (acc[e4][2] * a0 + base[e4 * 16 + g * 4 + 2] * a1) * inv;
        v.w = (acc[e4][3] * a0 + base[e4 * 16 + g * 4 + 3] * a1) * inv;
        *reinterpret_cast<float4*>(op + e4 * 16 + g * 4) = v;
      }
    }
  };

  // fused 17-round stream: rounds 0..RL-1 on tile lo, rest on tile hi
  constexpr int NRO = 17;
  loadq(QbL);
  issueK(0);
  issueV(0);

  for (int rd = 0; rd < NRO; ++rd) {
    const bool pre = (rd + 1 < NRO);
    const int nrd = rd + 1;
    const int nstr = (nrd < RL) ? nrd : nrd - RL;
    const bool lo = (rd < RL);
    round(lo ? QbL : QbH, lo ? rd : rd - RL, pre, nstr);
    if (rd == RL - 1) {
      merge_store(QbL);
      #pragma unroll
      for (int e4 = 0; e4 < 4; ++e4) acc[e4] = zero4;
      mrun = NEGBIG;
      lrun = 0.f;
      // drain all in-flight asm loads + merge stores so compiler loads in
      // loadq can't perturb the vmcnt invariant (regs stay valid; later
      // waits then pass instantly)
      asm volatile("s_waitcnt vmcnt(0)" ::: "memory");
      __builtin_amdgcn_sched_barrier(0);
      loadq(QbH);
    }
  }

  merge_store(QbH);
}

extern "C" void kernel_launch(void* const* d_in, const int* in_sizes, int n_in,
                              void* d_out, int out_size, void* d_ws, size_t ws_size,
                              hipStream_t stream) {
  const float* Q = (const float*)d_in[0];
  const float* K = (const float*)d_in[1];
  const float* V = (const float*)d_in[2];
  float* O = (float*)d_out;
  unsigned short* Kc = (unsigned short*)d_ws;
  unsigned short* Vt = (unsigned short*)((char*)d_ws + (size_t)Bc * Lc * Hc * Ec * 2);
  prep<<<dim3(2048), dim3(256), 0, stream>>>(K, V, (uint4*)Kc, Vt);
  dim3 grid(Bc * Hc * 16);   // 16 pairs x 32 bh; pair-major for XCD locality
  attn_fwd<<<grid, dim3(512), 0, stream>>>(Q, Kc, Vt, O);
}

// Round 24
// 49.250 us; speedup vs baseline: 1.1372x; 1.1372x over previous
//
#include <hip/hip_runtime.h>
#include <hip/hip_bf16.h>

typedef __attribute__((ext_vector_type(8))) short short8;
typedef __attribute__((ext_vector_type(4))) float f32x4;
typedef __attribute__((ext_vector_type(2))) unsigned uint2v;

#define MFMA16(a, b, c) __builtin_amdgcn_mfma_f32_16x16x32_bf16((a), (b), (c), 0, 0, 0)

constexpr int Bc = 2, Lc = 2048, Hc = 16, Ec = 64;
constexpr float LOG2E = 1.4426950408889634f;
constexpr float SCALE2 = 0.125f * LOG2E;   // fold log2(e): scores in log2 units
constexpr float NEGBIG = -3.0e38f;

union SW { short8 s8; unsigned u[4]; float4 f4; };

__device__ __forceinline__ unsigned cvtpk(float lo, float hi) {
  unsigned r;
  asm("v_cvt_pk_bf16_f32 %0, %1, %2" : "=v"(r) : "v"(lo), "v"(hi));
  return r;
}
__device__ __forceinline__ float exp2v(float x) {
  float r;
  asm("v_exp_f32 %0, %1" : "=v"(r) : "v"(x));
  return r;
}
__device__ __forceinline__ void plswap32(unsigned& a, unsigned& b) {
  uint2v r = __builtin_amdgcn_permlane32_swap(a, b, false, false);
  a = r[0]; b = r[1];
}
__device__ __forceinline__ void plswap16(unsigned& a, unsigned& b) {
  uint2v r = __builtin_amdgcn_permlane16_swap(a, b, false, false);
  a = r[0]; b = r[1];
}
__device__ __forceinline__ float bflymax(float x) {
  unsigned a = __builtin_bit_cast(unsigned, x), b = a;
  plswap16(a, b);
  float y = fmaxf(__builtin_bit_cast(float, a), __builtin_bit_cast(float, b));
  a = __builtin_bit_cast(unsigned, y); b = a;
  plswap32(a, b);
  return fmaxf(__builtin_bit_cast(float, a), __builtin_bit_cast(float, b));
}

// Fused prepass: K fp32->bf16 (RNE); V -> chunk-major Vt[bh][s/16][e][16] bf16.
__global__ __launch_bounds__(256)
void prep(const float* __restrict__ K, const float* __restrict__ V,
          uint4* __restrict__ Kb, unsigned short* __restrict__ Vt) {
  const int bid = blockIdx.x;
  const int t = threadIdx.x;
  if (bid < 2048) {
    const int i = bid * 256 + t;
    const float4* s = reinterpret_cast<const float4*>(K) + (size_t)i * 2;
    float4 a = s[0], b = s[1];
    uint4 o;
    o.x = cvtpk(a.x, a.y); o.y = cvtpk(a.z, a.w);
    o.z = cvtpk(b.x, b.y); o.w = cvtpk(b.z, b.w);
    Kb[i] = o;
  } else {
    const int vw = (bid - 2048) * 4 + (t >> 6);   // bh*128 + chunk
    const int l = t & 63;                          // e
    const int bh = vw >> 7;
    const int s0 = (vw & 127) * 16;
    const float* vp = V + ((size_t)(bh >> 4) * Lc + s0) * (Hc * Ec) +
                      (bh & 15) * Ec + l;
    float va[16];
    #pragma unroll
    for (int j = 0; j < 16; ++j) va[j] = vp[j * (Hc * Ec)];
    uint4 o0, o1;
    o0.x = cvtpk(va[0], va[1]);   o0.y = cvtpk(va[2], va[3]);
    o0.z = cvtpk(va[4], va[5]);   o0.w = cvtpk(va[6], va[7]);
    o1.x = cvtpk(va[8], va[9]);   o1.y = cvtpk(va[10], va[11]);
    o1.z = cvtpk(va[12], va[13]); o1.w = cvtpk(va[14], va[15]);
    uint4* dst = reinterpret_cast<uint4*>(Vt + ((size_t)vw * 64 + l) * 16);
    dst[0] = o0;
    dst[1] = o1;
  }
}

__global__ __launch_bounds__(512, 2)
void attn_fwd(const float* __restrict__ Qg, const unsigned short* __restrict__ Kb,
              const unsigned short* __restrict__ Vt, float* __restrict__ Og) {
  // smem (shorts), NT=128 s-tile double-buffered:
  //  kt[b]: [128][64] bf16 at b*8192, K row s at prow=pi(s), idx ^ ((prow&7)<<3)
  //  vt[b]: [64 e][128 s] bf16 at 16384 + b*8192, chunk slot = (s>>3) ^ (e&7)
  // merge scratch overlays the RETIRED buffer.
  __shared__ __align__(16) short smem[32768];

  // XCD-locality decode: bid = pair*32 + bh -> all 16 pair-blocks of a bh
  // share bid mod 8 (same XCD L2); the 2 blocks/CU share the same bh.
  const int bid = blockIdx.x;
  const int pair = bid >> 5;
  const int bh = bid & 31;
  const int h = bh & (Hc - 1);
  const int b = bh >> 4;
  const int iLo = pair;
  const int QbL = iLo * 64;
  const int QbH = (31 - pair) * 64;
  const int RL = (iLo + 2) >> 1;              // lo-tile rounds; RL + RH = 17

  const int t = threadIdx.x;
  const int w = t >> 6;        // 0..7
  const int qsub = w & 3;      // q sub-block (16 rows)
  const int par = w >> 2;      // 64-s half of the 128-row tile
  const int l = t & 63;
  const int n = l & 15;
  const int g = l >> 4;
  const int sp4 = ((g & 1) << 3) | ((g >> 1) << 2);  // pi(g)*4

  const f32x4 zero4 = {0.f, 0.f, 0.f, 0.f};
  short8 onesv;
  #pragma unroll
  for (int j = 0; j < 8; ++j) onesv[j] = (short)0x3F80;  // bf16 1.0

  // Q fragments (B-operand: col=q=lane&15, k=e=(lane>>4)*8+j)
  short8 qf[2];
  auto loadq = [&](int Qb) {
    const int q = Qb + qsub * 16 + n;
    const float* qp = Qg + ((size_t)(b * Lc + q) * Hc + h) * Ec + g * 8;
    SW a0, a1, b0, b1, r0, r1;
    a0.f4 = reinterpret_cast<const float4*>(qp)[0];
    a1.f4 = reinterpret_cast<const float4*>(qp)[1];
    b0.f4 = reinterpret_cast<const float4*>(qp + 32)[0];
    b1.f4 = reinterpret_cast<const float4*>(qp + 32)[1];
    r0.u[0] = cvtpk(a0.f4.x * SCALE2, a0.f4.y * SCALE2);
    r0.u[1] = cvtpk(a0.f4.z * SCALE2, a0.f4.w * SCALE2);
    r0.u[2] = cvtpk(a1.f4.x * SCALE2, a1.f4.y * SCALE2);
    r0.u[3] = cvtpk(a1.f4.z * SCALE2, a1.f4.w * SCALE2);
    r1.u[0] = cvtpk(b0.f4.x * SCALE2, b0.f4.y * SCALE2);
    r1.u[1] = cvtpk(b0.f4.z * SCALE2, b0.f4.w * SCALE2);
    r1.u[2] = cvtpk(b1.f4.x * SCALE2, b1.f4.y * SCALE2);
    r1.u[3] = cvtpk(b1.f4.z * SCALE2, b1.f4.w * SCALE2);
    qf[0] = r0.s8;
    qf[1] = r1.s8;
  };

  // acc[e4][r] = O^T[e = e4*16 + g*4 + r][q = n]; per-lane scalar m,l
  f32x4 acc[4] = {zero4, zero4, zero4, zero4};
  float mrun = NEGBIG, lrun = 0.f;

  // staging: 512 threads stage 128 rows of K (pi-permuted) and V^T per round
  const int srow = t >> 2;                               // 0..127
  const int prow = (srow & ~12) | ((srow & 4) << 1) | ((srow & 8) >> 1);
  const int kc0 = (t & 3) * 16;                          // 16-col bf16 chunk
  const int ve = l, vs0 = w * 16;                        // V^T: e=lane, 16 s rows

  float4 kA, kB, vA, vB;   // 4 x dwordx4 bf16

  // Forced-async bf16 stage: volatile asm loads issue HERE (unsinkable).
  auto issue = [&](int r0) {
    unsigned koff = (unsigned)((((b * Lc + r0 + srow) * Hc + h) * Ec + kc0) * 2);
    unsigned voff = (unsigned)(((bh * 128 + ((r0 + vs0) >> 4)) * 64 + ve) * 32);
    asm volatile(
      "global_load_dwordx4 %[k0], %[ko], %[kb]\n\t"
      "global_load_dwordx4 %[k1], %[ko], %[kb] offset:16\n\t"
      "global_load_dwordx4 %[v0], %[vo], %[vb]\n\t"
      "global_load_dwordx4 %[v1], %[vo], %[vb] offset:16"
      : [k0]"=v"(kA), [k1]"=v"(kB), [v0]"=v"(vA), [v1]"=v"(vB)
      : [ko]"v"(koff), [vo]"v"(voff), [kb]"s"(Kb), [vb]"s"(Vt)
      : "memory");
  };
  auto commit = [&](int buf) {
    asm volatile("s_waitcnt vmcnt(2)" ::: "memory");
    __builtin_amdgcn_sched_barrier(0);
    short* kt = smem + buf * 8192;
    *reinterpret_cast<short8*>(&kt[(prow * 64 + kc0) ^ ((prow & 7) << 3)]) =
        *reinterpret_cast<short8*>(&kA);
    *reinterpret_cast<short8*>(&kt[(prow * 64 + kc0 + 8) ^ ((prow & 7) << 3)]) =
        *reinterpret_cast<short8*>(&kB);
    asm volatile("s_waitcnt vmcnt(0)" ::: "memory");
    __builtin_amdgcn_sched_barrier(0);
    short* vt = smem + 16384 + buf * 8192;
    const int ch0 = vs0 >> 3;
    *reinterpret_cast<short8*>(&vt[ve * 128 + (((ch0 + 0) ^ (ve & 7)) << 3)]) =
        *reinterpret_cast<short8*>(&vA);
    *reinterpret_cast<short8*>(&vt[ve * 128 + (((ch0 + 1) ^ (ve & 7)) << 3)]) =
        *reinterpret_cast<short8*>(&vB);
  };

  // one 64q x 128s round (this wave: 16 q x 64 s half), swapped operands
  auto round = [&](int Qb, int str, int curb) {
    const int sb = str * 128 + par * 64;
    const int qtop = Qb + qsub * 16;
    if (sb > qtop + 15) return;
    const short* ktb = smem + curb * 8192;
    const short* vtb = smem + 16384 + curb * 8192;

    // QK^T swapped: D[s][q], col = q = n; 4 cb blocks x k=64
    f32x4 sc[4] = {zero4, zero4, zero4, zero4};
    __builtin_amdgcn_s_setprio(1);   // T5: favor this wave while MFMA-dense
    #pragma unroll
    for (int kc = 0; kc < 2; ++kc) {
      #pragma unroll
      for (int cb = 0; cb < 4; ++cb) {
        const int row = par * 64 + cb * 16 + n;
        const int idx = (row * 64 + kc * 32 + g * 8) ^ ((n & 7) << 3);
        short8 kf = *reinterpret_cast<const short8*>(&ktb[idx]);
        sc[cb] = MFMA16(kf, qf[kc], sc[cb]);
      }
    }
    __builtin_amdgcn_s_setprio(0);

    const int qg = qtop + n;
    if (sb + 63 > qtop) {
      #pragma unroll
      for (int cb = 0; cb < 4; ++cb)
        #pragma unroll
        for (int r = 0; r < 4; ++r)
          if (sb + cb * 16 + sp4 + r > qg) sc[cb][r] = NEGBIG;
    }

    // row max: 15 lane-local fmax + VALU butterfly
    float m8 = fmaxf(fmaxf(fmaxf(sc[0][0], sc[0][1]), fmaxf(sc[0][2], sc[0][3])),
                     fmaxf(fmaxf(sc[1][0], sc[1][1]), fmaxf(sc[1][2], sc[1][3])));
    m8 = fmaxf(m8, fmaxf(fmaxf(fmaxf(sc[2][0], sc[2][1]), fmaxf(sc[2][2], sc[2][3])),
                         fmaxf(fmaxf(sc[3][0], sc[3][1]), fmaxf(sc[3][2], sc[3][3]))));
    m8 = bflymax(m8);

    // exact-identity rescale skip
    const bool resc = !__all(m8 <= mrun);
    if (resc) {
      const float mn = fmaxf(mrun, m8);
      const float afac = exp2v(mrun - mn);
      mrun = mn;
      lrun *= afac;
      #pragma unroll
      for (int e4 = 0; e4 < 4; ++e4)
        #pragma unroll
        for (int r = 0; r < 4; ++r) acc[e4][r] *= afac;
    }

    // P = exp2(S - m) -> packed bf16
    unsigned ua[4], ub[4];
    #pragma unroll
    for (int cb = 0; cb < 4; ++cb) {
      ua[cb] = cvtpk(exp2v(sc[cb][0] - mrun), exp2v(sc[cb][1] - mrun));
      ub[cb] = cvtpk(exp2v(sc[cb][2] - mrun), exp2v(sc[cb][3] - mrun));
    }

    // P C-frag -> B-frag: pure-VALU permlane32 swaps
    plswap32(ua[0], ua[1]);
    plswap32(ub[0], ub[1]);
    plswap32(ua[2], ua[3]);
    plswap32(ub[2], ub[3]);
    SW pw0, pw1;
    pw0.u[0] = ua[0]; pw0.u[1] = ub[0]; pw0.u[2] = ua[1]; pw0.u[3] = ub[1];
    pw1.u[0] = ua[2]; pw1.u[1] = ub[2]; pw1.u[2] = ua[3]; pw1.u[3] = ub[3];

    // PV swapped + row sums: 10-MFMA cluster
    __builtin_amdgcn_s_setprio(1);
    #pragma unroll
    for (int e4 = 0; e4 < 4; ++e4) {
      const int e = e4 * 16 + n;
      const int slot0 = (par * 8 + g) ^ (e & 7);
      const int slot1 = (par * 8 + 4 + g) ^ (e & 7);
      short8 vf0 = *reinterpret_cast<const short8*>(&vtb[e * 128 + (slot0 << 3)]);
      acc[e4] = MFMA16(vf0, pw0.s8, acc[e4]);
      short8 vf1 = *reinterpret_cast<const short8*>(&vtb[e * 128 + (slot1 << 3)]);
      acc[e4] = MFMA16(vf1, pw1.s8, acc[e4]);
    }
    f32x4 rs = MFMA16(onesv, pw0.s8, zero4);
    rs = MFMA16(onesv, pw1.s8, rs);
    __builtin_amdgcn_s_setprio(0);
    lrun += rs[0];
  };

  // merge parities via scratch overlaid on the retired buffer `curb`
  auto merge_store = [&](int Qb, int curb) {
    float* sA = reinterpret_cast<float*>(smem) + curb * 4096;         // rows 0..31
    float* sB = reinterpret_cast<float*>(smem) + 8192 + curb * 4096;  // rows 32..63 + m + l
    __syncthreads();
    const int row = qsub * 16 + n;
    if (par == 1) {
      float* base = (row < 32) ? (sA + row * 68) : (sB + (row - 32) * 68);
      #pragma unroll
      for (int e4 = 0; e4 < 4; ++e4)
        #pragma unroll
        for (int r = 0; r < 4; ++r) base[e4 * 16 + g * 4 + r] = acc[e4][r];
      if (g == 0) {
        sB[2176 + row] = mrun;
        sB[2240 + row] = lrun;
      }
    }
    __syncthreads();
    if (par == 0) {
      const float* base = (row < 32) ? (sA + row * 68) : (sB + (row - 32) * 68);
      const float m1 = sB[2176 + row];
      const float l1 = sB[2240 + row];
      const float mm = fmaxf(mrun, m1);
      const float a0 = exp2v(mrun - mm);
      const float a1 = exp2v(m1 - mm);
      const float inv = 1.0f / (lrun * a0 + l1 * a1);
      const int q = Qb + row;
      float* op = Og + ((size_t)(b * Lc + q) * Hc + h) * Ec;
      #pragma unroll
      for (int e4 = 0; e4 < 4; ++e4) {
        float4 v;
        v.x = (acc[e4][0] * a0 + base[e4 * 16 + g * 4 + 0] * a1) * inv;
        v.y = (acc[e4][1] * a0 + base[e4 * 16 + g * 4 + 1] * a1) * inv;
        v.z = (acc[e4][2] * a0 + base[e4 * 16 + g * 4 + 2] * a1) * inv;
        v.w = (acc[e4][3] * a0 + base[e4 * 16 + g * 4 + 3] * a1) * inv;
        *reinterpret_cast<float4*>(op + e4 * 16 + g * 4) = v;
      }
    }
  };

  // fused 17-round stream: rounds 0..RL-1 on tile lo, rest on tile hi
  constexpr int NRO = 17;
  loadq(QbL);
  issue(0);
  commit(0);
  __syncthreads();

  int cur = 0;
  for (int rd = 0; rd < NRO; ++rd) {
    const bool pre = (rd + 1 < NRO);
    if (pre) {
      const int nrd = rd + 1;
      const int nstr = (nrd < RL) ? nrd : nrd - RL;
      issue(nstr * 128);
    }
    const bool lo = (rd < RL);
    round(lo ? QbL : QbH, lo ? rd : rd - RL, cur);
    if (rd == RL - 1) {
      merge_store(QbL, cur);   // scratch overlays the just-consumed buffer
      #pragma unroll
      for (int e4 = 0; e4 < 4; ++e4) acc[e4] = zero4;
      mrun = NEGBIG;
      lrun = 0.f;
      loadq(QbH);
    }
    if (pre) commit(cur ^ 1);
    __syncthreads();
    cur ^= 1;
  }

  merge_store(QbH, cur ^ 1);
}

extern "C" void kernel_launch(void* const* d_in, const int* in_sizes, int n_in,
                              void* d_out, int out_size, void* d_ws, size_t ws_size,
                              hipStream_t stream) {
  const float* Q = (const float*)d_in[0];
  const float* K = (const float*)d_in[1];
  const float* V = (const float*)d_in[2];
  float* O = (float*)d_out;
  unsigned short* Kb = (unsigned short*)d_ws;
  unsigned short* Vt = (unsigned short*)((char*)d_ws + (size_t)Bc * Lc * Hc * Ec * 2);
  prep<<<dim3(3072), dim3(256), 0, stream>>>(K, V, (uint4*)Kb, Vt);
  dim3 grid(Bc * Hc * 16);   // 16 pairs x 32 bh; pair-major for XCD locality
  attn_fwd<<<grid, dim3(512), 0, stream>>>(Q, Kb, Vt, O);
}